// Round 4
// baseline (262.189 us; speedup 1.0000x reference)
//
#include <hip/hip_runtime.h>

// MultiScaleRoIAlign: B=2, Nb=256 (R=512 rois), C=256, PH=PW=7, GRID=2.
// R3: LDS patch staging without integer divides (float-reciprocal row split),
// NC=8 channels/round (4 rounds, 8 barriers), wave-per-channel compute x2.

#define PHW 49
#define NCHUNK 8
#define CH 32            // channels per block
#define NC 8             // channels staged per round
#define PSIZE 1024       // floats per channel patch (worst case ~900)

__global__ __launch_bounds__(256) void msroi_kernel(
    const float* __restrict__ f0, const float* __restrict__ f1,
    const float* __restrict__ f2, const float* __restrict__ f3,
    const float* __restrict__ boxes, float* __restrict__ out)
{
    const int C = 256, Nb = 256;
    const int r = blockIdx.x;            // roi 0..511
    const int chunk = blockIdx.y;        // 0..7
    const int tid = threadIdx.x;
    const int b = r / Nb;

    // ---- per-roi params (uniform) ----
    const float x1b = boxes[r * 4 + 0];
    const float y1b = boxes[r * 4 + 1];
    const float x2b = boxes[r * 4 + 2];
    const float y2b = boxes[r * 4 + 3];
    const float area = fmaxf((x2b - x1b) * (y2b - y1b), 0.0f);
    const float s = sqrtf(area);
    float lv = floorf(4.0f + log2f(s / 224.0f + 1e-6f));
    lv = fminf(fmaxf(lv, 2.0f), 5.0f);
    const int lvl = (int)lv - 2;

    const float* feat;
    int H, W;
    float scale;
    switch (lvl) {
        case 0:  feat = f0; H = 200; W = 200; scale = 0.25f;    break;
        case 1:  feat = f1; H = 100; W = 100; scale = 0.125f;   break;
        case 2:  feat = f2; H = 50;  W = 50;  scale = 0.0625f;  break;
        default: feat = f3; H = 25;  W = 25;  scale = 0.03125f; break;
    }
    const int HW = H * W;

    const float x1 = x1b * scale, y1 = y1b * scale;
    const float x2 = x2b * scale, y2 = y2b * scale;
    const float roi_w = fmaxf(x2 - x1, 1.0f);
    const float roi_h = fmaxf(y2 - y1, 1.0f);
    const float bin_w = roi_w * (1.0f / 7.0f);
    const float bin_h = roi_h * (1.0f / 7.0f);

    // ---- patch bounds (uniform): samples at gy,gx in {0.25 .. 6.75} ----
    const float ys0 = fminf(fmaxf(y1 + 0.25f * bin_h, 0.0f), (float)(H - 1));
    const float ys1 = fminf(fmaxf(y1 + 6.75f * bin_h, 0.0f), (float)(H - 1));
    const float xs0 = fminf(fmaxf(x1 + 0.25f * bin_w, 0.0f), (float)(W - 1));
    const float xs1 = fminf(fmaxf(x1 + 6.75f * bin_w, 0.0f), (float)(W - 1));
    const int row0 = (int)floorf(ys0);
    const int row1 = min((int)floorf(ys1) + 1, H - 1);
    const int col0 = (int)floorf(xs0);
    const int col1 = min((int)floorf(xs1) + 1, W - 1);
    const int prows = row1 - row0 + 1;
    const int pcols = col1 - col0 + 1;
    const int psize = prows * pcols;
    const int wstride = W - pcols;                 // row jump in global plane
    const float inv_pcols = 1.0f / (float)pcols;   // exact recip for row split

    // ---- per-lane bin descriptors (patch-relative, channel-invariant) ----
    const int bin = tid & 63;            // lanes >=49 idle in compute
    const bool active = bin < PHW;
    int   offs[16];
    float wts[16];
    {
        const int bb = active ? bin : 0;
        const int ph = bb / 7;
        const int pw = bb - ph * 7;
#pragma unroll
        for (int g = 0; g < 4; ++g) {
            const int iy = g >> 1, ix = g & 1;
            const float gy = (float)ph + ((float)iy + 0.5f) * 0.5f;
            const float gx = (float)pw + ((float)ix + 0.5f) * 0.5f;
            const float y = y1 + gy * bin_h;
            const float x = x1 + gx * bin_w;
            const bool valid = (y >= -1.0f) && (y <= (float)H) &&
                               (x >= -1.0f) && (x <= (float)W);
            const float yc = fminf(fmaxf(y, 0.0f), (float)(H - 1));
            const float xc = fminf(fmaxf(x, 0.0f), (float)(W - 1));
            const int yl = (int)floorf(yc);
            const int xl = (int)floorf(xc);
            const int yh = min(yl + 1, H - 1);
            const int xh = min(xl + 1, W - 1);
            const float ly = yc - (float)yl;
            const float lx = xc - (float)xl;
            const float hy = 1.0f - ly, hx = 1.0f - lx;
            const float m = valid ? 0.25f : 0.0f;
            const int ry0 = (yl - row0) * pcols, ry1 = (yh - row0) * pcols;
            const int cx0 = xl - col0, cx1 = xh - col0;
            offs[g * 4 + 0] = ry0 + cx0;  wts[g * 4 + 0] = hy * hx * m;
            offs[g * 4 + 1] = ry0 + cx1;  wts[g * 4 + 1] = hy * lx * m;
            offs[g * 4 + 2] = ry1 + cx0;  wts[g * 4 + 2] = ly * hx * m;
            offs[g * 4 + 3] = ry1 + cx1;  wts[g * 4 + 3] = ly * lx * m;
        }
    }

    __shared__ float lds[NC * PSIZE];
    const int cslot = tid >> 6;          // wave id 0..3
    const int cbase = chunk * CH;
    const float* __restrict__ fch =
        feat + (size_t)(b * C + cbase) * HW + (row0 * W + col0);
    const size_t outBase = (size_t)r * C * PHW + (size_t)cbase * PHW;

    for (int cc = 0; cc < CH; cc += NC) {
        // ---- staging: ch-outer (uniform), element-inner, div-free ----
        for (int ch = 0; ch < NC; ++ch) {
            const float* __restrict__ gp = fch + (size_t)(cc + ch) * HW;
            float* __restrict__ lp = &lds[ch * PSIZE];
            for (int e = tid; e < psize; e += 256) {
                const int rr = (int)floorf(((float)e + 0.5f) * inv_pcols);
                lp[e] = gp[e + rr * wstride];
            }
        }
        __syncthreads();

        // ---- bilinear from LDS: wave w -> channels cc+w, cc+4+w ----
        if (active) {
#pragma unroll
            for (int half = 0; half < 2; ++half) {
                const int ch = cslot + half * 4;
                const float* __restrict__ p = &lds[ch * PSIZE];
                float acc = 0.0f;
#pragma unroll
                for (int k = 0; k < 16; ++k)
                    acc += wts[k] * p[offs[k]];
                out[outBase + (size_t)(cc + ch) * PHW + bin] = acc;
            }
        }
        __syncthreads();
    }
}

extern "C" void kernel_launch(void* const* d_in, const int* in_sizes, int n_in,
                              void* d_out, int out_size, void* d_ws, size_t ws_size,
                              hipStream_t stream) {
    const float* f0 = (const float*)d_in[0];
    const float* f1 = (const float*)d_in[1];
    const float* f2 = (const float*)d_in[2];
    const float* f3 = (const float*)d_in[3];
    const float* boxes = (const float*)d_in[4];
    float* out = (float*)d_out;

    const int R = in_sizes[4] / 4;   // 512 rois
    dim3 grid(R, NCHUNK);
    msroi_kernel<<<grid, 256, 0, stream>>>(f0, f1, f2, f3, boxes, out);
}

// Round 5
// 179.638 us; speedup vs baseline: 1.4595x; 1.4595x over previous
//
#include <hip/hip_runtime.h>

// MultiScaleRoIAlign: B=2, Nb=256 (R=512 rois), C=256, PH=PW=7, GRID=2.
// R4: register-batched staging (16 unconditional loads in flight per wave),
// NC=4 channels/round, 16 KB LDS -> 8 blocks/CU (wave-capped).
// Patch offsets (4 per thread) computed once; psize provably <= ~900 < 1024.

#define PHW 49
#define NCHUNK 8
#define CH 32            // channels per block
#define NC 4             // channels staged per round
#define PSIZE 1024       // floats per channel patch slab

__global__ __launch_bounds__(256) void msroi_kernel(
    const float* __restrict__ f0, const float* __restrict__ f1,
    const float* __restrict__ f2, const float* __restrict__ f3,
    const float* __restrict__ boxes, float* __restrict__ out)
{
    const int C = 256, Nb = 256;
    const int r = blockIdx.x;            // roi 0..511
    const int chunk = blockIdx.y;        // 0..7
    const int tid = threadIdx.x;
    const int b = r / Nb;

    // ---- per-roi params (uniform) ----
    const float x1b = boxes[r * 4 + 0];
    const float y1b = boxes[r * 4 + 1];
    const float x2b = boxes[r * 4 + 2];
    const float y2b = boxes[r * 4 + 3];
    const float area = fmaxf((x2b - x1b) * (y2b - y1b), 0.0f);
    const float s = sqrtf(area);
    float lv = floorf(4.0f + log2f(s / 224.0f + 1e-6f));
    lv = fminf(fmaxf(lv, 2.0f), 5.0f);
    const int lvl = (int)lv - 2;

    const float* feat;
    int H, W;
    float scale;
    switch (lvl) {
        case 0:  feat = f0; H = 200; W = 200; scale = 0.25f;    break;
        case 1:  feat = f1; H = 100; W = 100; scale = 0.125f;   break;
        case 2:  feat = f2; H = 50;  W = 50;  scale = 0.0625f;  break;
        default: feat = f3; H = 25;  W = 25;  scale = 0.03125f; break;
    }
    const int HW = H * W;

    const float x1 = x1b * scale, y1 = y1b * scale;
    const float x2 = x2b * scale, y2 = y2b * scale;
    const float roi_w = fmaxf(x2 - x1, 1.0f);
    const float roi_h = fmaxf(y2 - y1, 1.0f);
    const float bin_w = roi_w * (1.0f / 7.0f);
    const float bin_h = roi_h * (1.0f / 7.0f);

    // ---- patch bounds (uniform): samples at gy,gx in {0.25 .. 6.75} ----
    const float ys0 = fminf(fmaxf(y1 + 0.25f * bin_h, 0.0f), (float)(H - 1));
    const float ys1 = fminf(fmaxf(y1 + 6.75f * bin_h, 0.0f), (float)(H - 1));
    const float xs0 = fminf(fmaxf(x1 + 0.25f * bin_w, 0.0f), (float)(W - 1));
    const float xs1 = fminf(fmaxf(x1 + 6.75f * bin_w, 0.0f), (float)(W - 1));
    const int row0 = (int)floorf(ys0);
    const int row1 = min((int)floorf(ys1) + 1, H - 1);
    const int col0 = (int)floorf(xs0);
    const int col1 = min((int)floorf(xs1) + 1, W - 1);
    const int prows = row1 - row0 + 1;
    const int pcols = col1 - col0 + 1;
    const int psize = prows * pcols;
    const int wstride = W - pcols;                 // row jump in global plane
    const float inv_pcols = 1.0f / (float)pcols;

    // ---- per-thread staging offsets (loop-invariant, computed once) ----
    // e_k = tid + k*256 (< PSIZE always); global offset clamped to patch.
    int goff[4];
#pragma unroll
    for (int k = 0; k < 4; ++k) {
        const int e = tid + k * 256;
        const int ec = min(e, psize - 1);
        const int rr = (int)floorf(((float)ec + 0.5f) * inv_pcols);
        goff[k] = ec + rr * wstride;
    }

    // ---- per-lane bin descriptors (patch-relative, channel-invariant) ----
    const int bin = tid & 63;            // lanes >=49 idle in compute
    const bool active = bin < PHW;
    int   offs[16];
    float wts[16];
    {
        const int bb = active ? bin : 0;
        const int ph = bb / 7;
        const int pw = bb - ph * 7;
#pragma unroll
        for (int g = 0; g < 4; ++g) {
            const int iy = g >> 1, ix = g & 1;
            const float gy = (float)ph + ((float)iy + 0.5f) * 0.5f;
            const float gx = (float)pw + ((float)ix + 0.5f) * 0.5f;
            const float y = y1 + gy * bin_h;
            const float x = x1 + gx * bin_w;
            const bool valid = (y >= -1.0f) && (y <= (float)H) &&
                               (x >= -1.0f) && (x <= (float)W);
            const float yc = fminf(fmaxf(y, 0.0f), (float)(H - 1));
            const float xc = fminf(fmaxf(x, 0.0f), (float)(W - 1));
            const int yl = (int)floorf(yc);
            const int xl = (int)floorf(xc);
            const int yh = min(yl + 1, H - 1);
            const int xh = min(xl + 1, W - 1);
            const float ly = yc - (float)yl;
            const float lx = xc - (float)xl;
            const float hy = 1.0f - ly, hx = 1.0f - lx;
            const float m = valid ? 0.25f : 0.0f;
            const int ry0 = (yl - row0) * pcols, ry1 = (yh - row0) * pcols;
            const int cx0 = xl - col0, cx1 = xh - col0;
            offs[g * 4 + 0] = ry0 + cx0;  wts[g * 4 + 0] = hy * hx * m;
            offs[g * 4 + 1] = ry0 + cx1;  wts[g * 4 + 1] = hy * lx * m;
            offs[g * 4 + 2] = ry1 + cx0;  wts[g * 4 + 2] = ly * hx * m;
            offs[g * 4 + 3] = ry1 + cx1;  wts[g * 4 + 3] = ly * lx * m;
        }
    }

    __shared__ float lds[NC * PSIZE];
    const int cslot = tid >> 6;          // wave id 0..3 -> channel slot
    const int cbase = chunk * CH;
    const float* __restrict__ fch =
        feat + (size_t)(b * C + cbase) * HW + (row0 * W + col0);
    const size_t outBase = (size_t)r * C * PHW + (size_t)cbase * PHW;

    for (int cc = 0; cc < CH; cc += NC) {
        // ---- staging: 16 unconditional loads -> regs, then 16 LDS writes ----
        float buf[NC][4];
#pragma unroll
        for (int ch = 0; ch < NC; ++ch) {
            const float* __restrict__ gp = fch + (size_t)(cc + ch) * HW;
#pragma unroll
            for (int k = 0; k < 4; ++k)
                buf[ch][k] = gp[goff[k]];
        }
#pragma unroll
        for (int ch = 0; ch < NC; ++ch) {
#pragma unroll
            for (int k = 0; k < 4; ++k)
                lds[ch * PSIZE + tid + k * 256] = buf[ch][k];
        }
        __syncthreads();

        // ---- bilinear from LDS: wave w -> channel cc+w ----
        if (active) {
            const float* __restrict__ p = &lds[cslot * PSIZE];
            float acc = 0.0f;
#pragma unroll
            for (int k = 0; k < 16; ++k)
                acc += wts[k] * p[offs[k]];
            out[outBase + (size_t)(cc + cslot) * PHW + bin] = acc;
        }
        __syncthreads();
    }
}

extern "C" void kernel_launch(void* const* d_in, const int* in_sizes, int n_in,
                              void* d_out, int out_size, void* d_ws, size_t ws_size,
                              hipStream_t stream) {
    const float* f0 = (const float*)d_in[0];
    const float* f1 = (const float*)d_in[1];
    const float* f2 = (const float*)d_in[2];
    const float* f3 = (const float*)d_in[3];
    const float* boxes = (const float*)d_in[4];
    float* out = (float*)d_out;

    const int R = in_sizes[4] / 4;   // 512 rois
    dim3 grid(R, NCHUNK);
    msroi_kernel<<<grid, 256, 0, stream>>>(f0, f1, f2, f3, boxes, out);
}